// Round 14
// baseline (166.141 us; speedup 1.0000x reference)
//
#include <hip/hip_runtime.h>
#include <hip/hip_bf16.h>

typedef __hip_bfloat16 bf16;
typedef short short8 __attribute__((ext_vector_type(8)));
typedef float floatx4 __attribute__((ext_vector_type(4)));
typedef unsigned uintx4 __attribute__((ext_vector_type(4)));
typedef unsigned short ushort;

#define MFMA __builtin_amdgcn_mfma_f32_16x16x32_bf16

#define BATCH 4
#define SEQ   1024
#define DIM   1024
#define HEADS 16
#define HD    64
#define RS    72    // padded LDS row stride (shorts) for fp32-path B / P

// scores = -(sq_i - 2 q.k + sq_j)*0.125. Analytic max = self-score (dist=0),
// so p = exp(0.25*dot - 0.125*sq_j - 0.125*sq_i) = exp(-dist^2/8) in (0,1]
// is the EXACT softmax numerator — no running max needed. r14: computed as
// exp2(0.25*log2e*dot - 0.125*log2e*(sq_j+sq_i)) — same v_exp_f32 hw op,
// one fewer VALU per element.
//
// LESSON LEDGER:
// r1: occupancy is NOT the limiter (at >=2 blk/CU). GEMMs staging bound.
// r2: cooperative grid.sync fusion = 383us. Dead end.
// r3: nontemporal stores neutral; producer->consumer scratch reads fine.
// r4/r5: big register prefetch spills regardless of launch_bounds. DEAD.
// r6: global_load_lds A-staging: 203->187us (+14% on gemm<0>).
// r7: both-sides swizzle: conflicts 7.8M->1.5M, time flat (hidden).
// r8: one-barrier/iter neutral — the vmcnt(0) DRAIN is the cost.
// r9: B-staging by DMA (conv_all pre-converts weights): 186.5->171.7us.
// r10: counted-vmcnt depth-2 pipeline FAILED (races). PARKED.
// r11/r12: Q+V fused (A staged once, 32 MFMA per 8 DMA per drain at
//      2 blk/CU): 171.7->158.0us.
// r13: wide gemm_out (128x128, 256 blocks = 1 blk/CU) REGRESSED ->164us:
//      the fusion lever REQUIRES >=2 co-resident blocks/CU to cover the
//      drain. Reverted.
// r14 (this): r12 config + attn softmax exp2 prescale (fma+v_exp per
//      element instead of fma+add+mul+v_exp; attn is VALU-dep-bound).

__device__ __forceinline__ float b2f(ushort u) {
    union { unsigned i; float f; } x; x.i = (unsigned)u << 16; return x.f;
}
__device__ __forceinline__ ushort f2b(float f) {   // RTNE
    union { float f; unsigned i; } x; x.f = f;
    return (ushort)((x.i + 0x7FFFu + ((x.i >> 16) & 1u)) >> 16);
}

__device__ __forceinline__ void nts16(void* p, uint4 v) {
    uintx4 x; x.x = v.x; x.y = v.y; x.z = v.z; x.w = v.w;
    __builtin_nontemporal_store(x, (uintx4*)p);
}
__device__ __forceinline__ void nts16f(void* p, float4 v) {
    floatx4 x; x.x = v.x; x.y = v.y; x.z = v.z; x.w = v.w;
    __builtin_nontemporal_store(x, (floatx4*)p);
}
__device__ __forceinline__ void nts2(ushort* p, ushort v) {
    __builtin_nontemporal_store(v, p);
}

// async global->LDS, 16B per lane; LDS dest = wave-uniform base + lane*16
__device__ __forceinline__ void gload16(const ushort* gp, ushort* lp) {
    __builtin_amdgcn_global_load_lds(
        (const __attribute__((address_space(1))) unsigned*)gp,
        (__attribute__((address_space(3))) unsigned*)lp, 16, 0, 0);
}

// 8 fp32 (two uint4) -> 8 bf16 via hw packed cvt (v_cvt_pk_bf16_f32, RTNE)
__device__ __forceinline__ short8 cvt8(uint4 a, uint4 b) {
    const float* f0 = (const float*)&a;
    const float* f1 = (const float*)&b;
    union { __hip_bfloat162 h; unsigned u; } c0, c1, c2, c3;
    float2 p;
    p.x = f0[0]; p.y = f0[1]; c0.h = __float22bfloat162_rn(p);
    p.x = f0[2]; p.y = f0[3]; c1.h = __float22bfloat162_rn(p);
    p.x = f1[0]; p.y = f1[1]; c2.h = __float22bfloat162_rn(p);
    p.x = f1[2]; p.y = f1[3]; c3.h = __float22bfloat162_rn(p);
    short8 s;
    unsigned* su = (unsigned*)&s;
    su[0] = c0.u; su[1] = c1.u; su[2] = c2.u; su[3] = c3.u;
    return s;
}

// ---------------------------------------------------------------------------
// conv_all: fp32 -> bf16 (RTNE). blocks [0,2048): x; [2048,2560): Wq;
// [2560,3072): Wv; [3072,3584): Wo (skipped when !doWo).
// ---------------------------------------------------------------------------
__global__ __launch_bounds__(256)
void conv_all(const float* __restrict__ x,  const float* __restrict__ Wq,
              const float* __restrict__ Wv, const float* __restrict__ Wo,
              ushort* __restrict__ xb,  ushort* __restrict__ wqb,
              ushort* __restrict__ wvb, ushort* __restrict__ wob, int doWo)
{
    const int b = blockIdx.x;
    const float* src; ushort* dst; size_t off;
    if (b < 2048)      { src = x;  dst = xb;  off = (size_t)b * 256; }
    else if (b < 2560) { src = Wq; dst = wqb; off = (size_t)(b - 2048) * 256; }
    else if (b < 3072) { src = Wv; dst = wvb; off = (size_t)(b - 2560) * 256; }
    else               { if (!doWo) return;
                         src = Wo; dst = wob; off = (size_t)(b - 3072) * 256; }
    off += threadIdx.x;
    const uint4* sv = (const uint4*)src;
    uint4 a = sv[off * 2], c = sv[off * 2 + 1];
    short8 s = cvt8(a, c);
    nts16(dst + off * 8, *(uint4*)&s);
}

// ---------------------------------------------------------------------------
// gemm_qv: fused Q+V projection (r12-proven). [Qh; Vt] = xb @ {Wq,Wv}^T + b.
// 128x(64+64) per block: A-band staged ONCE, 32 MFMA per 8 DMA per iter.
// ---------------------------------------------------------------------------
__global__ __launch_bounds__(256, 2)
void gemm_qv(const ushort* __restrict__ Ab,
             const ushort* __restrict__ Wqb, const ushort* __restrict__ Wvb,
             const float* __restrict__ bq, const float* __restrict__ bv,
             ushort* __restrict__ Qd, ushort* __restrict__ Vd,
             float* __restrict__ sqQ)
{
    __shared__ __align__(16) ushort SMEM[32768];   // 64 KB exactly
    const int t = threadIdx.x;
    const int w = t >> 6, lane = t & 63;
    const int lr = lane & 15, quad = lane >> 4;
    const int n0 = blockIdx.x * 64;
    const int m0 = blockIdx.y * 128;
    const int mw = (w >> 1) * 64, nw = (w & 1) * 32;
    const int arow = lane >> 3;
    const int acS  = ((lane & 7) ^ arow) * 8;   // swizzled source col (shorts)

    ushort* Acur = SMEM;            // [128][64]
    ushort* Anxt = SMEM + 8192;
    ushort* BQc  = SMEM + 16384;    // [64][64]
    ushort* BVc  = SMEM + 20480;
    ushort* BQn  = SMEM + 24576;
    ushort* BVn  = SMEM + 28672;

    // prologue: stage tile 0
    #pragma unroll
    for (int i = 0; i < 4; ++i) {
        const int chunk = w * 4 + i;
        gload16(Ab + (size_t)(m0 + chunk * 8 + arow) * DIM + acS,
                Acur + chunk * 512);
    }
    #pragma unroll
    for (int i = 0; i < 2; ++i) {
        const int c = w * 2 + i;
        gload16(Wqb + (size_t)(n0 + c * 8 + arow) * DIM + acS, BQc + c * 512);
        gload16(Wvb + (size_t)(n0 + c * 8 + arow) * DIM + acS, BVc + c * 512);
    }
    __syncthreads();

    floatx4 accQ[4][2], accV[4][2];
    const floatx4 fz = {0.f, 0.f, 0.f, 0.f};
    #pragma unroll
    for (int i = 0; i < 4; ++i)
        #pragma unroll
        for (int j = 0; j < 2; ++j) { accQ[i][j] = fz; accV[i][j] = fz; }

    for (int kt = 0; kt < 16; ++kt) {
        if (kt < 15) {
            const int k0 = (kt + 1) * 64;
            #pragma unroll
            for (int i = 0; i < 4; ++i) {
                const int chunk = w * 4 + i;
                gload16(Ab + (size_t)(m0 + chunk * 8 + arow) * DIM + k0 + acS,
                        Anxt + chunk * 512);
            }
            #pragma unroll
            for (int i = 0; i < 2; ++i) {
                const int c = w * 2 + i;
                gload16(Wqb + (size_t)(n0 + c * 8 + arow) * DIM + k0 + acS,
                        BQn + c * 512);
                gload16(Wvb + (size_t)(n0 + c * 8 + arow) * DIM + k0 + acS,
                        BVn + c * 512);
            }
        }
        #pragma unroll
        for (int ks = 0; ks < 2; ++ks) {
            const int csw = (((ks << 2) | quad) ^ (lr & 7)) * 8;
            short8 af[4], bqf[2], bvf[2];
            #pragma unroll
            for (int tm = 0; tm < 4; ++tm)
                af[tm] = *(const short8*)&Acur[(mw + tm * 16 + lr) * 64 + csw];
            #pragma unroll
            for (int tn = 0; tn < 2; ++tn) {
                const int rowb = (nw + tn * 16 + lr) * 64 + csw;
                bqf[tn] = *(const short8*)&BQc[rowb];
                bvf[tn] = *(const short8*)&BVc[rowb];
            }
            #pragma unroll
            for (int tm = 0; tm < 4; ++tm)
                #pragma unroll
                for (int tn = 0; tn < 2; ++tn) {
                    accQ[tm][tn] = MFMA(af[tm], bqf[tn], accQ[tm][tn], 0, 0, 0);
                    accV[tm][tn] = MFMA(af[tm], bvf[tn], accV[tm][tn], 0, 0, 0);
                }
        }
        __syncthreads();   // drains tile(kt+1) DMA; reads of cur done
        ushort* tp;
        tp = Acur; Acur = Anxt; Anxt = tp;
        tp = BQc;  BQc  = BQn;  BQn  = tp;
        tp = BVc;  BVc  = BVn;  BVn  = tp;
    }

    const int bb = m0 >> 10, ii0 = m0 & 1023;
    const int head = blockIdx.x;          // 16 heads
    const int bh = bb * HEADS + head;

    // ---- Q epilogue (D layout col=lane&15, row=quad*4+reg) ----
    #pragma unroll
    for (int tn = 0; tn < 2; ++tn) {
        const float bval = bq[n0 + nw + tn * 16 + lr];
        #pragma unroll
        for (int tm = 0; tm < 4; ++tm)
            #pragma unroll
            for (int r = 0; r < 4; ++r)
                SMEM[(mw + tm * 16 + quad * 4 + r) * 80 + nw + tn * 16 + lr] =
                    f2b(accQ[tm][tn][r] + bval);
    }
    __syncthreads();
    {   // per-row ||q||^2 from the bf16 tile (matches attn's b2f semantics)
        const int row = t >> 1, half = t & 1;
        float s = 0.f;
        #pragma unroll
        for (int c = 0; c < 4; ++c) {
            uint4 kk = *(const uint4*)&SMEM[row * 80 + half * 32 + c * 8];
            const ushort* u = (const ushort*)&kk;
            #pragma unroll
            for (int e = 0; e < 8; ++e) { float f = b2f(u[e]); s += f * f; }
        }
        s += __shfl_xor(s, 1);
        if (half == 0) sqQ[(size_t)bh * SEQ + ii0 + row] = s;
    }
    #pragma unroll
    for (int it = 0; it < 4; ++it) {
        const int cid = it * 256 + t;
        const int row = cid >> 3, col8 = (cid & 7) * 8;
        nts16(Qd + ((size_t)bh * SEQ + ii0 + row) * HD + col8,
              *(const uint4*)&SMEM[row * 80 + col8]);
    }
    __syncthreads();   // Q reads (incl. sq) done before V overwrites SMEM

    // ---- V epilogue (transposed store) ----
    #pragma unroll
    for (int tn = 0; tn < 2; ++tn) {
        const float bval = bv[n0 + nw + tn * 16 + lr];
        #pragma unroll
        for (int tm = 0; tm < 4; ++tm)
            #pragma unroll
            for (int r = 0; r < 4; ++r)
                SMEM[(nw + tn * 16 + lr) * 144 + mw + tm * 16 + quad * 4 + r] =
                    f2b(accV[tm][tn][r] + bval);
    }
    __syncthreads();
    #pragma unroll
    for (int it = 0; it < 4; ++it) {
        const int cid = it * 256 + t;
        const int row = cid >> 4, col8 = (cid & 15) * 8;
        nts16(Vd + ((size_t)bh * HD + row) * SEQ + ii0 + col8,
              *(const uint4*)&SMEM[row * 144 + col8]);
    }
}

// ---------------------------------------------------------------------------
// gemm_out (r12-proven narrow). C = Oh @ Wo^T + bias, fp32 out. 128x64 tile.
// A: gload_lds dbuf + swizzle. B: BDMA=1 bf16 DMA; BDMA=0 fp32 reg+cvt8.
// ---------------------------------------------------------------------------
template<int BDMA>
__global__ __launch_bounds__(256, 3)
void gemm_out(const ushort* __restrict__ Ab,
              const ushort* __restrict__ Wb, const float* __restrict__ Wf,
              const float* __restrict__ bias, float* __restrict__ Fd)
{
    __shared__ __align__(16) ushort SMEM[2 * 8192 + 2 * 64 * RS];
    const int t = threadIdx.x;
    const int w = t >> 6, lane = t & 63;
    const int lr = lane & 15, quad = lane >> 4;
    const int n0 = blockIdx.x * 64;
    const int m0 = blockIdx.y * 128;
    const int mw = (w >> 1) * 64, nw = (w & 1) * 32;
    const int ar = t >> 3, ac8 = (t & 7) * 8;
    const int arow = lane >> 3;
    const int acS  = ((lane & 7) ^ arow) * 8;

    ushort* Acur = SMEM;
    ushort* Anxt = SMEM + 8192;
    ushort* Bcur = SMEM + 16384;
    ushort* Bnxt = SMEM + 16384 + (BDMA ? 4096 : 64 * RS);

    uint4 wpre[4];
    #pragma unroll
    for (int i = 0; i < 4; ++i) {
        const int chunk = w * 4 + i;
        gload16(Ab + (size_t)(m0 + chunk * 8 + arow) * DIM + acS,
                Acur + chunk * 512);
    }
    if (BDMA) {
        #pragma unroll
        for (int i = 0; i < 2; ++i) {
            const int c = w * 2 + i;
            gload16(Wb + (size_t)(n0 + c * 8 + arow) * DIM + acS,
                    Bcur + c * 512);
        }
    } else {
        #pragma unroll
        for (int c = 0; c < 2; ++c) {
            const float* wp = Wf + (size_t)(n0 + c * 32 + ar) * DIM + ac8;
            wpre[2 * c]     = *(const uint4*)wp;
            wpre[2 * c + 1] = *(const uint4*)(wp + 4);
        }
        #pragma unroll
        for (int c = 0; c < 2; ++c)
            *(short8*)&Bcur[(c * 32 + ar) * RS + ac8] = cvt8(wpre[2 * c], wpre[2 * c + 1]);
    }
    __syncthreads();

    floatx4 acc[4][2];
    const floatx4 fz = {0.f, 0.f, 0.f, 0.f};
    #pragma unroll
    for (int i = 0; i < 4; ++i)
        #pragma unroll
        for (int j = 0; j < 2; ++j) acc[i][j] = fz;

    for (int kt = 0; kt < 16; ++kt) {
        if (kt < 15) {
            const int k0 = (kt + 1) * 64;
            #pragma unroll
            for (int i = 0; i < 4; ++i) {
                const int chunk = w * 4 + i;
                gload16(Ab + (size_t)(m0 + chunk * 8 + arow) * DIM + k0 + acS,
                        Anxt + chunk * 512);
            }
            if (BDMA) {
                #pragma unroll
                for (int i = 0; i < 2; ++i) {
                    const int c = w * 2 + i;
                    gload16(Wb + (size_t)(n0 + c * 8 + arow) * DIM + k0 + acS,
                            Bnxt + c * 512);
                }
            } else {
                #pragma unroll
                for (int c = 0; c < 2; ++c) {
                    const float* wp = Wf + (size_t)(n0 + c * 32 + ar) * DIM + k0 + ac8;
                    wpre[2 * c]     = *(const uint4*)wp;
                    wpre[2 * c + 1] = *(const uint4*)(wp + 4);
                }
            }
        }
        #pragma unroll
        for (int ks = 0; ks < 2; ++ks) {
            const int csw = (((ks << 2) | quad) ^ (lr & 7)) * 8;
            short8 af[4], bfx[2];
            #pragma unroll
            for (int tm = 0; tm < 4; ++tm)
                af[tm] = *(const short8*)&Acur[(mw + tm * 16 + lr) * 64 + csw];
            #pragma unroll
            for (int tn = 0; tn < 2; ++tn) {
                const int rowb = nw + tn * 16 + lr;
                if (BDMA) bfx[tn] = *(const short8*)&Bcur[rowb * 64 + csw];
                else      bfx[tn] = *(const short8*)&Bcur[rowb * RS + ks * 32 + quad * 8];
            }
            #pragma unroll
            for (int tm = 0; tm < 4; ++tm)
                #pragma unroll
                for (int tn = 0; tn < 2; ++tn)
                    acc[tm][tn] = MFMA(af[tm], bfx[tn], acc[tm][tn], 0, 0, 0);
        }
        if (!BDMA && kt < 15) {
            #pragma unroll
            for (int c = 0; c < 2; ++c)
                *(short8*)&Bnxt[(c * 32 + ar) * RS + ac8] = cvt8(wpre[2 * c], wpre[2 * c + 1]);
        }
        __syncthreads();
        ushort* tp;
        tp = Acur; Acur = Anxt; Anxt = tp;
        tp = Bcur; Bcur = Bnxt; Bnxt = tp;
    }

    float* TF = (float*)SMEM;
    #pragma unroll
    for (int pass = 0; pass < 2; ++pass) {
        __syncthreads();
        if ((w >> 1) == pass) {
            #pragma unroll
            for (int tn = 0; tn < 2; ++tn) {
                const float bval = bias[n0 + nw + tn * 16 + lr];
                #pragma unroll
                for (int tm = 0; tm < 4; ++tm)
                    #pragma unroll
                    for (int r = 0; r < 4; ++r)
                        TF[(tm * 16 + quad * 4 + r) * 68 + nw + tn * 16 + lr] =
                            acc[tm][tn][r] + bval;
            }
        }
        __syncthreads();
        #pragma unroll
        for (int it = 0; it < 4; ++it) {
            const int cid = it * 256 + t;
            const int row = cid >> 4, c4 = (cid & 15) * 4;
            nts16f(Fd + (size_t)(m0 + pass * 64 + row) * DIM + n0 + c4,
                   *(const float4*)&TF[row * 68 + c4]);
        }
    }
}

// ---------------------------------------------------------------------------
// MFMA flash L2-attention, i-tile 128 (r8/r9 structure; r14: exp2 prescale):
// sq precomputed; K/V gload_lds dbuf with source swizzle; 1 barrier/j-tile.
// 512 blocks, XCD swizzle bh=id&63. Q bf16 [bh][n][64], Vt bf16 [bh][d][n].
// ---------------------------------------------------------------------------
__global__ __launch_bounds__(256, 3)
void attn_mfma(const ushort* __restrict__ Q, const ushort* __restrict__ Vt,
               const float* __restrict__ sqG, ushort* __restrict__ O)
{
    __shared__ __align__(16) ushort Ps[128 * RS];   // Q stage, then P [i][j]
    __shared__ __align__(16) ushort KV[4 * 4096];   // K0 V0 K1 V1, [64][64]

    const int t = threadIdx.x;
    const int w = t >> 6, lane = t & 63;
    const int lr = lane & 15, quad = lane >> 4;
    const int id = blockIdx.x;
    const int bh = id & 63;            // 512 blocks: 8 i-blocks x 64 bh
    const int i0 = (id >> 6) * 128;
    const ushort* __restrict__ Qp = Q  + (size_t)bh * SEQ * HD;
    const ushort* __restrict__ Vp = Vt + (size_t)bh * HD * SEQ;
    const float*  __restrict__ sqB = sqG + (size_t)bh * SEQ;

    // exp2 prescale constants: exp(y) = exp2(y*log2e)
    const float C_DOT = 0.25f * 1.4426950408889634f;     // 0.25*log2e
    const float C_SQ  = -0.125f * 1.4426950408889634f;   // -0.125*log2e

    const int arow = lane >> 3;
    const int acS  = ((lane & 7) ^ arow) * 8;

    ushort* Kcur = KV;
    ushort* Vcur = KV + 4096;
    ushort* Knxt = KV + 8192;
    ushort* Vnxt = KV + 12288;

    #pragma unroll
    for (int i = 0; i < 2; ++i) {
        const int c = w + i * 4;
        gload16(Qp + (size_t)(c * 8 + arow) * HD + acS, Kcur + c * 512);
        gload16(Vp + (size_t)(c * 8 + arow) * SEQ + acS, Vcur + c * 512);
    }
    #pragma unroll
    for (int it = 0; it < 4; ++it) {
        const int cid = it * 256 + t;
        const int r = cid >> 3, c8 = (cid & 7) * 8;
        *(uint4*)&Ps[r * RS + c8] = *(const uint4*)(Qp + (size_t)(i0 + r) * HD + c8);
    }
    __syncthreads();   // Ps(Q) visible; tile-0 DMA drained

    short8 qa[2][2];
    #pragma unroll
    for (int tm = 0; tm < 2; ++tm)
        #pragma unroll
        for (int ks = 0; ks < 2; ++ks)
            qa[tm][ks] = *(const short8*)&Ps[(w * 32 + tm * 16 + lr) * RS + ks * 32 + quad * 8];
    float sqi[2][4];   // pre-scaled: -0.125*log2e*||q_i||^2
    #pragma unroll
    for (int tm = 0; tm < 2; ++tm)
        #pragma unroll
        for (int r = 0; r < 4; ++r)
            sqi[tm][r] = C_SQ * sqB[i0 + w * 32 + tm * 16 + quad * 4 + r];

    floatx4 oacc[2][4];
    const floatx4 fz = {0.f, 0.f, 0.f, 0.f};
    float lrow[2][4] = {};
    #pragma unroll
    for (int tm = 0; tm < 2; ++tm)
        #pragma unroll
        for (int td = 0; td < 4; ++td) oacc[tm][td] = fz;

    for (int jt = 0; jt < 16; ++jt) {
        if (jt < 15) {
            const int j0n = (jt + 1) * 64;
            #pragma unroll
            for (int i = 0; i < 2; ++i) {
                const int c = w + i * 4;
                gload16(Qp + (size_t)(j0n + c * 8 + arow) * HD + acS, Knxt + c * 512);
                gload16(Vp + (size_t)(c * 8 + arow) * SEQ + j0n + acS, Vnxt + c * 512);
            }
        }
        float sq4[4];   // pre-scaled: -0.125*log2e*||q_j||^2
        #pragma unroll
        for (int tn = 0; tn < 4; ++tn) sq4[tn] = C_SQ * sqB[jt * 64 + tn * 16 + lr];

        short8 kb[4][2];
        #pragma unroll
        for (int tn = 0; tn < 4; ++tn)
            #pragma unroll
            for (int ks = 0; ks < 2; ++ks) {
                const int row = tn * 16 + lr;
                kb[tn][ks] = *(const short8*)&Kcur[row * 64 + ((((ks << 2) | quad)) ^ (lr & 7)) * 8];
            }

        #pragma unroll
        for (int tm = 0; tm < 2; ++tm) {
            floatx4 sacc[4];
            #pragma unroll
            for (int tn = 0; tn < 4; ++tn) {
                floatx4 a = MFMA(qa[tm][0], kb[tn][0], fz, 0, 0, 0);
                sacc[tn]  = MFMA(qa[tm][1], kb[tn][1], a, 0, 0, 0);
            }
            float sc[4][4];
            #pragma unroll
            for (int tn = 0; tn < 4; ++tn) {
                #pragma unroll
                for (int r = 0; r < 4; ++r)
                    sc[tn][r] = exp2f(C_DOT * sacc[tn][r] + (sq4[tn] + sqi[tm][r]));
            }
            #pragma unroll
            for (int r = 0; r < 4; ++r)
                lrow[tm][r] += sc[0][r] + sc[1][r] + sc[2][r] + sc[3][r];
            #pragma unroll
            for (int tp = 0; tp < 2; ++tp)
                #pragma unroll
                for (int r = 0; r < 4; ++r) {
                    float2 fp; fp.x = sc[2 * tp][r]; fp.y = sc[2 * tp + 1][r];
                    union { __hip_bfloat162 h; unsigned u; } cv;
                    cv.h = __float22bfloat162_rn(fp);
                    const int rowb = (w * 32 + tm * 16 + quad * 4 + r) * RS + lr;
                    Ps[rowb + (2 * tp) * 16]     = (ushort)(cv.u & 0xffffu);
                    Ps[rowb + (2 * tp + 1) * 16] = (ushort)(cv.u >> 16);
                }
        }
        short8 pa[2][2], vb[4][2];
        #pragma unroll
        for (int tm = 0; tm < 2; ++tm)
            #pragma unroll
            for (int ks = 0; ks < 2; ++ks)
                pa[tm][ks] = *(const short8*)&Ps[(w * 32 + tm * 16 + lr) * RS + ks * 32 + quad * 8];
        #pragma unroll
        for (int td = 0; td < 4; ++td)
            #pragma unroll
            for (int ks = 0; ks < 2; ++ks) {
                const int row = td * 16 + lr;
                vb[td][ks] = *(const short8*)&Vcur[row * 64 + ((((ks << 2) | quad)) ^ (lr & 7)) * 8];
            }
        #pragma unroll
        for (int tm = 0; tm < 2; ++tm)
            #pragma unroll
            for (int td = 0; td < 4; ++td) {
                oacc[tm][td] = MFMA(pa[tm][0], vb[td][0], oacc[tm][td], 0, 0, 0);
                oacc[tm][td] = MFMA(pa[tm][1], vb[td][1], oacc[tm][td], 0, 0, 0);
            }
        __syncthreads();   // reads of Kcur/Vcur done; drains next-tile DMA
        ushort* tp2;
        tp2 = Kcur; Kcur = Knxt; Knxt = tp2;
        tp2 = Vcur; Vcur = Vnxt; Vnxt = tp2;
    }

    const int bb = bh >> 4, head = bh & 15;
    #pragma unroll
    for (int tm = 0; tm < 2; ++tm)
        #pragma unroll
        for (int r = 0; r < 4; ++r) {
            float l = lrow[tm][r];
            l += __shfl_xor(l, 1);
            l += __shfl_xor(l, 2);
            l += __shfl_xor(l, 4);
            l += __shfl_xor(l, 8);
            const float inv = 1.f / l;
            const int row = i0 + w * 32 + tm * 16 + quad * 4 + r;
            #pragma unroll
            for (int td = 0; td < 4; ++td) {
                nts2(O + (size_t)(bb * SEQ + row) * DIM + head * HD + td * 16 + lr,
                     f2b(oacc[tm][td][r] * inv));
            }
        }
}

extern "C" void kernel_launch(void* const* d_in, const int* in_sizes, int n_in,
                              void* d_out, int out_size, void* d_ws, size_t ws_size,
                              hipStream_t stream)
{
    const float* x  = (const float*)d_in[0];
    const float* Wq = (const float*)d_in[1];
    const float* bq = (const float*)d_in[2];
    const float* Wv = (const float*)d_in[3];
    const float* bv = (const float*)d_in[4];
    const float* Wo = (const float*)d_in[5];
    const float* bo = (const float*)d_in[6];

    // ws: Qh 8MB | Vt 8MB | R 8MB (xb for QV, then Oh) | [Wob 2MB if room]
    ushort* Qh = (ushort*)d_ws;
    ushort* Vt = Qh + (size_t)BATCH * HEADS * SEQ * HD;
    ushort* R  = Vt + (size_t)BATCH * HEADS * SEQ * HD;
    const size_t WS3 = (size_t)3 * BATCH * HEADS * SEQ * HD * 2;   // 24 MB
    const size_t WOB = (size_t)DIM * DIM * 2;                      // 2 MB
    const int doWo = ws_size >= WS3 + WOB;
    ushort* Wob = (ushort*)((char*)d_ws + WS3);

    // d_out (16MB) as pre-phase scratch (fully overwritten by gemm_out):
    // Wqb [0,2MB) | Wvb [2,4MB) | sq [4,4.25MB)
    ushort* Wqb = (ushort*)d_out;
    ushort* Wvb = Wqb + (size_t)DIM * DIM;
    float*  sqG = (float*)(Wvb + (size_t)DIM * DIM);

    conv_all<<<3584, 256, 0, stream>>>(x, Wq, Wv, Wo, R, Wqb, Wvb, Wob, doWo);
    gemm_qv<<<dim3(16, 32), 256, 0, stream>>>(R, Wqb, Wvb, bq, bv, Qh, Vt, sqG);
    attn_mfma<<<512, 256, 0, stream>>>(Qh, Vt, sqG, R);   // Oh overwrites xb
    if (doWo) {
        gemm_out<1><<<dim3(16, 32), 256, 0, stream>>>(R, Wob, nullptr, bo,
                                                      (float*)d_out);
    } else {
        gemm_out<0><<<dim3(16, 32), 256, 0, stream>>>(R, nullptr, Wo, bo,
                                                      (float*)d_out);
    }
}

// Round 15
// 158.007 us; speedup vs baseline: 1.0515x; 1.0515x over previous
//
#include <hip/hip_runtime.h>
#include <hip/hip_bf16.h>

typedef __hip_bfloat16 bf16;
typedef short short8 __attribute__((ext_vector_type(8)));
typedef float floatx4 __attribute__((ext_vector_type(4)));
typedef unsigned uintx4 __attribute__((ext_vector_type(4)));
typedef unsigned short ushort;

#define MFMA __builtin_amdgcn_mfma_f32_16x16x32_bf16

#define BATCH 4
#define SEQ   1024
#define DIM   1024
#define HEADS 16
#define HD    64
#define RS    72    // padded LDS row stride (shorts) for fp32-path B / P

// scores = -(sq_i - 2 q.k + sq_j)*0.125. Analytic max = self-score (dist=0),
// so p = exp(0.25*dot - 0.125*sq_j - 0.125*sq_i) = exp(-dist^2/8) in (0,1]
// is the EXACT softmax numerator — no running max needed.
//
// LESSON LEDGER (final):
// r1: occupancy is NOT the limiter (at >=2 blk/CU). GEMMs staging bound.
// r2: cooperative grid.sync fusion = 383us. Dead end.
// r3: nontemporal stores neutral; producer->consumer scratch reads fine.
// r4/r5: big register prefetch spills regardless of launch_bounds. DEAD.
// r6: global_load_lds A-staging: 203->187us (+14% on gemm<0>).
// r7: both-sides swizzle: conflicts 7.8M->1.5M, time flat (hidden).
// r8: one-barrier/iter neutral — the vmcnt(0) DRAIN is the cost.
// r9: B-staging by DMA (conv_all pre-converts weights): 186.5->171.7us.
// r10: counted-vmcnt depth-2 pipeline FAILED (races; raw s_barrier has no
//      fence at HIP level). PARKED — needs race-screening infra.
// r11/r12: Q+V fused (A staged once, 32 MFMA per 8 DMA per drain at
//      2 blk/CU): 171.7->158.0us. BEST.
// r13: wide gemm_out (1 blk/CU) REGRESSED: fusion lever needs >=2 blk/CU.
// r14: attn exp2 prescale null (attn is P-store-layout bound: 32 scalar
//      ds_write_b16/lane/tile from MFMA D->A transpose, not mul-count).
//      Proper fix = swapped-QK^T in-register softmax (T12) — parked with
//      r10 (same race-screening requirement).
// r15 (this): exact r12 revert — session best, every component verified.

__device__ __forceinline__ float b2f(ushort u) {
    union { unsigned i; float f; } x; x.i = (unsigned)u << 16; return x.f;
}
__device__ __forceinline__ ushort f2b(float f) {   // RTNE
    union { float f; unsigned i; } x; x.f = f;
    return (ushort)((x.i + 0x7FFFu + ((x.i >> 16) & 1u)) >> 16);
}

__device__ __forceinline__ void nts16(void* p, uint4 v) {
    uintx4 x; x.x = v.x; x.y = v.y; x.z = v.z; x.w = v.w;
    __builtin_nontemporal_store(x, (uintx4*)p);
}
__device__ __forceinline__ void nts16f(void* p, float4 v) {
    floatx4 x; x.x = v.x; x.y = v.y; x.z = v.z; x.w = v.w;
    __builtin_nontemporal_store(x, (floatx4*)p);
}
__device__ __forceinline__ void nts2(ushort* p, ushort v) {
    __builtin_nontemporal_store(v, p);
}

// async global->LDS, 16B per lane; LDS dest = wave-uniform base + lane*16
__device__ __forceinline__ void gload16(const ushort* gp, ushort* lp) {
    __builtin_amdgcn_global_load_lds(
        (const __attribute__((address_space(1))) unsigned*)gp,
        (__attribute__((address_space(3))) unsigned*)lp, 16, 0, 0);
}

// 8 fp32 (two uint4) -> 8 bf16 via hw packed cvt (v_cvt_pk_bf16_f32, RTNE)
__device__ __forceinline__ short8 cvt8(uint4 a, uint4 b) {
    const float* f0 = (const float*)&a;
    const float* f1 = (const float*)&b;
    union { __hip_bfloat162 h; unsigned u; } c0, c1, c2, c3;
    float2 p;
    p.x = f0[0]; p.y = f0[1]; c0.h = __float22bfloat162_rn(p);
    p.x = f0[2]; p.y = f0[3]; c1.h = __float22bfloat162_rn(p);
    p.x = f1[0]; p.y = f1[1]; c2.h = __float22bfloat162_rn(p);
    p.x = f1[2]; p.y = f1[3]; c3.h = __float22bfloat162_rn(p);
    short8 s;
    unsigned* su = (unsigned*)&s;
    su[0] = c0.u; su[1] = c1.u; su[2] = c2.u; su[3] = c3.u;
    return s;
}

// ---------------------------------------------------------------------------
// conv_all: fp32 -> bf16 (RTNE). blocks [0,2048): x; [2048,2560): Wq;
// [2560,3072): Wv; [3072,3584): Wo (skipped when !doWo).
// ---------------------------------------------------------------------------
__global__ __launch_bounds__(256)
void conv_all(const float* __restrict__ x,  const float* __restrict__ Wq,
              const float* __restrict__ Wv, const float* __restrict__ Wo,
              ushort* __restrict__ xb,  ushort* __restrict__ wqb,
              ushort* __restrict__ wvb, ushort* __restrict__ wob, int doWo)
{
    const int b = blockIdx.x;
    const float* src; ushort* dst; size_t off;
    if (b < 2048)      { src = x;  dst = xb;  off = (size_t)b * 256; }
    else if (b < 2560) { src = Wq; dst = wqb; off = (size_t)(b - 2048) * 256; }
    else if (b < 3072) { src = Wv; dst = wvb; off = (size_t)(b - 2560) * 256; }
    else               { if (!doWo) return;
                         src = Wo; dst = wob; off = (size_t)(b - 3072) * 256; }
    off += threadIdx.x;
    const uint4* sv = (const uint4*)src;
    uint4 a = sv[off * 2], c = sv[off * 2 + 1];
    short8 s = cvt8(a, c);
    nts16(dst + off * 8, *(uint4*)&s);
}

// ---------------------------------------------------------------------------
// gemm_qv: fused Q+V projection (r12-proven). [Qh; Vt] = xb @ {Wq,Wv}^T + b.
// 128x(64+64) per block: A-band staged ONCE, 32 MFMA per 8 DMA per iter,
// 512 blocks = 2 blk/CU (required for the fusion lever to pay — r13).
// ---------------------------------------------------------------------------
__global__ __launch_bounds__(256, 2)
void gemm_qv(const ushort* __restrict__ Ab,
             const ushort* __restrict__ Wqb, const ushort* __restrict__ Wvb,
             const float* __restrict__ bq, const float* __restrict__ bv,
             ushort* __restrict__ Qd, ushort* __restrict__ Vd,
             float* __restrict__ sqQ)
{
    __shared__ __align__(16) ushort SMEM[32768];   // 64 KB exactly
    const int t = threadIdx.x;
    const int w = t >> 6, lane = t & 63;
    const int lr = lane & 15, quad = lane >> 4;
    const int n0 = blockIdx.x * 64;
    const int m0 = blockIdx.y * 128;
    const int mw = (w >> 1) * 64, nw = (w & 1) * 32;
    const int arow = lane >> 3;
    const int acS  = ((lane & 7) ^ arow) * 8;   // swizzled source col (shorts)

    ushort* Acur = SMEM;            // [128][64]
    ushort* Anxt = SMEM + 8192;
    ushort* BQc  = SMEM + 16384;    // [64][64]
    ushort* BVc  = SMEM + 20480;
    ushort* BQn  = SMEM + 24576;
    ushort* BVn  = SMEM + 28672;

    // prologue: stage tile 0
    #pragma unroll
    for (int i = 0; i < 4; ++i) {
        const int chunk = w * 4 + i;
        gload16(Ab + (size_t)(m0 + chunk * 8 + arow) * DIM + acS,
                Acur + chunk * 512);
    }
    #pragma unroll
    for (int i = 0; i < 2; ++i) {
        const int c = w * 2 + i;
        gload16(Wqb + (size_t)(n0 + c * 8 + arow) * DIM + acS, BQc + c * 512);
        gload16(Wvb + (size_t)(n0 + c * 8 + arow) * DIM + acS, BVc + c * 512);
    }
    __syncthreads();

    floatx4 accQ[4][2], accV[4][2];
    const floatx4 fz = {0.f, 0.f, 0.f, 0.f};
    #pragma unroll
    for (int i = 0; i < 4; ++i)
        #pragma unroll
        for (int j = 0; j < 2; ++j) { accQ[i][j] = fz; accV[i][j] = fz; }

    for (int kt = 0; kt < 16; ++kt) {
        if (kt < 15) {
            const int k0 = (kt + 1) * 64;
            #pragma unroll
            for (int i = 0; i < 4; ++i) {
                const int chunk = w * 4 + i;
                gload16(Ab + (size_t)(m0 + chunk * 8 + arow) * DIM + k0 + acS,
                        Anxt + chunk * 512);
            }
            #pragma unroll
            for (int i = 0; i < 2; ++i) {
                const int c = w * 2 + i;
                gload16(Wqb + (size_t)(n0 + c * 8 + arow) * DIM + k0 + acS,
                        BQn + c * 512);
                gload16(Wvb + (size_t)(n0 + c * 8 + arow) * DIM + k0 + acS,
                        BVn + c * 512);
            }
        }
        #pragma unroll
        for (int ks = 0; ks < 2; ++ks) {
            const int csw = (((ks << 2) | quad) ^ (lr & 7)) * 8;
            short8 af[4], bqf[2], bvf[2];
            #pragma unroll
            for (int tm = 0; tm < 4; ++tm)
                af[tm] = *(const short8*)&Acur[(mw + tm * 16 + lr) * 64 + csw];
            #pragma unroll
            for (int tn = 0; tn < 2; ++tn) {
                const int rowb = (nw + tn * 16 + lr) * 64 + csw;
                bqf[tn] = *(const short8*)&BQc[rowb];
                bvf[tn] = *(const short8*)&BVc[rowb];
            }
            #pragma unroll
            for (int tm = 0; tm < 4; ++tm)
                #pragma unroll
                for (int tn = 0; tn < 2; ++tn) {
                    accQ[tm][tn] = MFMA(af[tm], bqf[tn], accQ[tm][tn], 0, 0, 0);
                    accV[tm][tn] = MFMA(af[tm], bvf[tn], accV[tm][tn], 0, 0, 0);
                }
        }
        __syncthreads();   // drains tile(kt+1) DMA; reads of cur done
        ushort* tp;
        tp = Acur; Acur = Anxt; Anxt = tp;
        tp = BQc;  BQc  = BQn;  BQn  = tp;
        tp = BVc;  BVc  = BVn;  BVn  = tp;
    }

    const int bb = m0 >> 10, ii0 = m0 & 1023;
    const int head = blockIdx.x;          // 16 heads
    const int bh = bb * HEADS + head;

    // ---- Q epilogue (D layout col=lane&15, row=quad*4+reg) ----
    #pragma unroll
    for (int tn = 0; tn < 2; ++tn) {
        const float bval = bq[n0 + nw + tn * 16 + lr];
        #pragma unroll
        for (int tm = 0; tm < 4; ++tm)
            #pragma unroll
            for (int r = 0; r < 4; ++r)
                SMEM[(mw + tm * 16 + quad * 4 + r) * 80 + nw + tn * 16 + lr] =
                    f2b(accQ[tm][tn][r] + bval);
    }
    __syncthreads();
    {   // per-row ||q||^2 from the bf16 tile (matches attn's b2f semantics)
        const int row = t >> 1, half = t & 1;
        float s = 0.f;
        #pragma unroll
        for (int c = 0; c < 4; ++c) {
            uint4 kk = *(const uint4*)&SMEM[row * 80 + half * 32 + c * 8];
            const ushort* u = (const ushort*)&kk;
            #pragma unroll
            for (int e = 0; e < 8; ++e) { float f = b2f(u[e]); s += f * f; }
        }
        s += __shfl_xor(s, 1);
        if (half == 0) sqQ[(size_t)bh * SEQ + ii0 + row] = s;
    }
    #pragma unroll
    for (int it = 0; it < 4; ++it) {
        const int cid = it * 256 + t;
        const int row = cid >> 3, col8 = (cid & 7) * 8;
        nts16(Qd + ((size_t)bh * SEQ + ii0 + row) * HD + col8,
              *(const uint4*)&SMEM[row * 80 + col8]);
    }
    __syncthreads();   // Q reads (incl. sq) done before V overwrites SMEM

    // ---- V epilogue (transposed store) ----
    #pragma unroll
    for (int tn = 0; tn < 2; ++tn) {
        const float bval = bv[n0 + nw + tn * 16 + lr];
        #pragma unroll
        for (int tm = 0; tm < 4; ++tm)
            #pragma unroll
            for (int r = 0; r < 4; ++r)
                SMEM[(nw + tn * 16 + lr) * 144 + mw + tm * 16 + quad * 4 + r] =
                    f2b(accV[tm][tn][r] + bval);
    }
    __syncthreads();
    #pragma unroll
    for (int it = 0; it < 4; ++it) {
        const int cid = it * 256 + t;
        const int row = cid >> 4, col8 = (cid & 15) * 8;
        nts16(Vd + ((size_t)bh * HD + row) * SEQ + ii0 + col8,
              *(const uint4*)&SMEM[row * 144 + col8]);
    }
}

// ---------------------------------------------------------------------------
// gemm_out (r12-proven narrow). C = Oh @ Wo^T + bias, fp32 out. 128x64 tile,
// 512 blocks = 2+/CU. A: gload_lds dbuf + swizzle. B: BDMA=1 bf16 DMA;
// BDMA=0 fp32 reg+cvt8 fallback.
// ---------------------------------------------------------------------------
template<int BDMA>
__global__ __launch_bounds__(256, 3)
void gemm_out(const ushort* __restrict__ Ab,
              const ushort* __restrict__ Wb, const float* __restrict__ Wf,
              const float* __restrict__ bias, float* __restrict__ Fd)
{
    __shared__ __align__(16) ushort SMEM[2 * 8192 + 2 * 64 * RS];
    const int t = threadIdx.x;
    const int w = t >> 6, lane = t & 63;
    const int lr = lane & 15, quad = lane >> 4;
    const int n0 = blockIdx.x * 64;
    const int m0 = blockIdx.y * 128;
    const int mw = (w >> 1) * 64, nw = (w & 1) * 32;
    const int ar = t >> 3, ac8 = (t & 7) * 8;
    const int arow = lane >> 3;
    const int acS  = ((lane & 7) ^ arow) * 8;

    ushort* Acur = SMEM;
    ushort* Anxt = SMEM + 8192;
    ushort* Bcur = SMEM + 16384;
    ushort* Bnxt = SMEM + 16384 + (BDMA ? 4096 : 64 * RS);

    uint4 wpre[4];
    #pragma unroll
    for (int i = 0; i < 4; ++i) {
        const int chunk = w * 4 + i;
        gload16(Ab + (size_t)(m0 + chunk * 8 + arow) * DIM + acS,
                Acur + chunk * 512);
    }
    if (BDMA) {
        #pragma unroll
        for (int i = 0; i < 2; ++i) {
            const int c = w * 2 + i;
            gload16(Wb + (size_t)(n0 + c * 8 + arow) * DIM + acS,
                    Bcur + c * 512);
        }
    } else {
        #pragma unroll
        for (int c = 0; c < 2; ++c) {
            const float* wp = Wf + (size_t)(n0 + c * 32 + ar) * DIM + ac8;
            wpre[2 * c]     = *(const uint4*)wp;
            wpre[2 * c + 1] = *(const uint4*)(wp + 4);
        }
        #pragma unroll
        for (int c = 0; c < 2; ++c)
            *(short8*)&Bcur[(c * 32 + ar) * RS + ac8] = cvt8(wpre[2 * c], wpre[2 * c + 1]);
    }
    __syncthreads();

    floatx4 acc[4][2];
    const floatx4 fz = {0.f, 0.f, 0.f, 0.f};
    #pragma unroll
    for (int i = 0; i < 4; ++i)
        #pragma unroll
        for (int j = 0; j < 2; ++j) acc[i][j] = fz;

    for (int kt = 0; kt < 16; ++kt) {
        if (kt < 15) {
            const int k0 = (kt + 1) * 64;
            #pragma unroll
            for (int i = 0; i < 4; ++i) {
                const int chunk = w * 4 + i;
                gload16(Ab + (size_t)(m0 + chunk * 8 + arow) * DIM + k0 + acS,
                        Anxt + chunk * 512);
            }
            if (BDMA) {
                #pragma unroll
                for (int i = 0; i < 2; ++i) {
                    const int c = w * 2 + i;
                    gload16(Wb + (size_t)(n0 + c * 8 + arow) * DIM + k0 + acS,
                            Bnxt + c * 512);
                }
            } else {
                #pragma unroll
                for (int c = 0; c < 2; ++c) {
                    const float* wp = Wf + (size_t)(n0 + c * 32 + ar) * DIM + k0 + ac8;
                    wpre[2 * c]     = *(const uint4*)wp;
                    wpre[2 * c + 1] = *(const uint4*)(wp + 4);
                }
            }
        }
        #pragma unroll
        for (int ks = 0; ks < 2; ++ks) {
            const int csw = (((ks << 2) | quad) ^ (lr & 7)) * 8;
            short8 af[4], bfx[2];
            #pragma unroll
            for (int tm = 0; tm < 4; ++tm)
                af[tm] = *(const short8*)&Acur[(mw + tm * 16 + lr) * 64 + csw];
            #pragma unroll
            for (int tn = 0; tn < 2; ++tn) {
                const int rowb = nw + tn * 16 + lr;
                if (BDMA) bfx[tn] = *(const short8*)&Bcur[rowb * 64 + csw];
                else      bfx[tn] = *(const short8*)&Bcur[rowb * RS + ks * 32 + quad * 8];
            }
            #pragma unroll
            for (int tm = 0; tm < 4; ++tm)
                #pragma unroll
                for (int tn = 0; tn < 2; ++tn)
                    acc[tm][tn] = MFMA(af[tm], bfx[tn], acc[tm][tn], 0, 0, 0);
        }
        if (!BDMA && kt < 15) {
            #pragma unroll
            for (int c = 0; c < 2; ++c)
                *(short8*)&Bnxt[(c * 32 + ar) * RS + ac8] = cvt8(wpre[2 * c], wpre[2 * c + 1]);
        }
        __syncthreads();
        ushort* tp;
        tp = Acur; Acur = Anxt; Anxt = tp;
        tp = Bcur; Bcur = Bnxt; Bnxt = tp;
    }

    float* TF = (float*)SMEM;
    #pragma unroll
    for (int pass = 0; pass < 2; ++pass) {
        __syncthreads();
        if ((w >> 1) == pass) {
            #pragma unroll
            for (int tn = 0; tn < 2; ++tn) {
                const float bval = bias[n0 + nw + tn * 16 + lr];
                #pragma unroll
                for (int tm = 0; tm < 4; ++tm)
                    #pragma unroll
                    for (int r = 0; r < 4; ++r)
                        TF[(tm * 16 + quad * 4 + r) * 68 + nw + tn * 16 + lr] =
                            acc[tm][tn][r] + bval;
            }
        }
        __syncthreads();
        #pragma unroll
        for (int it = 0; it < 4; ++it) {
            const int cid = it * 256 + t;
            const int row = cid >> 4, c4 = (cid & 15) * 4;
            nts16f(Fd + (size_t)(m0 + pass * 64 + row) * DIM + n0 + c4,
                   *(const float4*)&TF[row * 68 + c4]);
        }
    }
}

// ---------------------------------------------------------------------------
// MFMA flash L2-attention, i-tile 128 (r8/r9/r12-proven):
// sq precomputed; K/V gload_lds dbuf with source swizzle; 1 barrier/j-tile.
// 512 blocks, XCD swizzle bh=id&63. Q bf16 [bh][n][64], Vt bf16 [bh][d][n].
// ---------------------------------------------------------------------------
__global__ __launch_bounds__(256, 3)
void attn_mfma(const ushort* __restrict__ Q, const ushort* __restrict__ Vt,
               const float* __restrict__ sqG, ushort* __restrict__ O)
{
    __shared__ __align__(16) ushort Ps[128 * RS];   // Q stage, then P [i][j]
    __shared__ __align__(16) ushort KV[4 * 4096];   // K0 V0 K1 V1, [64][64]

    const int t = threadIdx.x;
    const int w = t >> 6, lane = t & 63;
    const int lr = lane & 15, quad = lane >> 4;
    const int id = blockIdx.x;
    const int bh = id & 63;            // 512 blocks: 8 i-blocks x 64 bh
    const int i0 = (id >> 6) * 128;
    const ushort* __restrict__ Qp = Q  + (size_t)bh * SEQ * HD;
    const ushort* __restrict__ Vp = Vt + (size_t)bh * HD * SEQ;
    const float*  __restrict__ sqB = sqG + (size_t)bh * SEQ;

    const int arow = lane >> 3;
    const int acS  = ((lane & 7) ^ arow) * 8;

    ushort* Kcur = KV;
    ushort* Vcur = KV + 4096;
    ushort* Knxt = KV + 8192;
    ushort* Vnxt = KV + 12288;

    #pragma unroll
    for (int i = 0; i < 2; ++i) {
        const int c = w + i * 4;
        gload16(Qp + (size_t)(c * 8 + arow) * HD + acS, Kcur + c * 512);
        gload16(Vp + (size_t)(c * 8 + arow) * SEQ + acS, Vcur + c * 512);
    }
    #pragma unroll
    for (int it = 0; it < 4; ++it) {
        const int cid = it * 256 + t;
        const int r = cid >> 3, c8 = (cid & 7) * 8;
        *(uint4*)&Ps[r * RS + c8] = *(const uint4*)(Qp + (size_t)(i0 + r) * HD + c8);
    }
    __syncthreads();   // Ps(Q) visible; tile-0 DMA drained

    short8 qa[2][2];
    #pragma unroll
    for (int tm = 0; tm < 2; ++tm)
        #pragma unroll
        for (int ks = 0; ks < 2; ++ks)
            qa[tm][ks] = *(const short8*)&Ps[(w * 32 + tm * 16 + lr) * RS + ks * 32 + quad * 8];
    float sqi[2][4];
    #pragma unroll
    for (int tm = 0; tm < 2; ++tm)
        #pragma unroll
        for (int r = 0; r < 4; ++r)
            sqi[tm][r] = sqB[i0 + w * 32 + tm * 16 + quad * 4 + r];

    floatx4 oacc[2][4];
    const floatx4 fz = {0.f, 0.f, 0.f, 0.f};
    float lrow[2][4] = {};
    #pragma unroll
    for (int tm = 0; tm < 2; ++tm)
        #pragma unroll
        for (int td = 0; td < 4; ++td) oacc[tm][td] = fz;

    for (int jt = 0; jt < 16; ++jt) {
        if (jt < 15) {
            const int j0n = (jt + 1) * 64;
            #pragma unroll
            for (int i = 0; i < 2; ++i) {
                const int c = w + i * 4;
                gload16(Qp + (size_t)(j0n + c * 8 + arow) * HD + acS, Knxt + c * 512);
                gload16(Vp + (size_t)(c * 8 + arow) * SEQ + j0n + acS, Vnxt + c * 512);
            }
        }
        float sq4[4];
        #pragma unroll
        for (int tn = 0; tn < 4; ++tn) sq4[tn] = sqB[jt * 64 + tn * 16 + lr];

        short8 kb[4][2];
        #pragma unroll
        for (int tn = 0; tn < 4; ++tn)
            #pragma unroll
            for (int ks = 0; ks < 2; ++ks) {
                const int row = tn * 16 + lr;
                kb[tn][ks] = *(const short8*)&Kcur[row * 64 + ((((ks << 2) | quad)) ^ (lr & 7)) * 8];
            }

        #pragma unroll
        for (int tm = 0; tm < 2; ++tm) {
            floatx4 sacc[4];
            #pragma unroll
            for (int tn = 0; tn < 4; ++tn) {
                floatx4 a = MFMA(qa[tm][0], kb[tn][0], fz, 0, 0, 0);
                sacc[tn]  = MFMA(qa[tm][1], kb[tn][1], a, 0, 0, 0);
            }
            float sc[4][4];
            #pragma unroll
            for (int tn = 0; tn < 4; ++tn) {
                const float msq = -0.125f * sq4[tn];
                #pragma unroll
                for (int r = 0; r < 4; ++r)
                    sc[tn][r] = __expf(0.25f * sacc[tn][r] + msq - 0.125f * sqi[tm][r]);
            }
            #pragma unroll
            for (int r = 0; r < 4; ++r)
                lrow[tm][r] += sc[0][r] + sc[1][r] + sc[2][r] + sc[3][r];
            #pragma unroll
            for (int tp = 0; tp < 2; ++tp)
                #pragma unroll
                for (int r = 0; r < 4; ++r) {
                    float2 fp; fp.x = sc[2 * tp][r]; fp.y = sc[2 * tp + 1][r];
                    union { __hip_bfloat162 h; unsigned u; } cv;
                    cv.h = __float22bfloat162_rn(fp);
                    const int rowb = (w * 32 + tm * 16 + quad * 4 + r) * RS + lr;
                    Ps[rowb + (2 * tp) * 16]     = (ushort)(cv.u & 0xffffu);
                    Ps[rowb + (2 * tp + 1) * 16] = (ushort)(cv.u >> 16);
                }
        }
        short8 pa[2][2], vb[4][2];
        #pragma unroll
        for (int tm = 0; tm < 2; ++tm)
            #pragma unroll
            for (int ks = 0; ks < 2; ++ks)
                pa[tm][ks] = *(const short8*)&Ps[(w * 32 + tm * 16 + lr) * RS + ks * 32 + quad * 8];
        #pragma unroll
        for (int td = 0; td < 4; ++td)
            #pragma unroll
            for (int ks = 0; ks < 2; ++ks) {
                const int row = td * 16 + lr;
                vb[td][ks] = *(const short8*)&Vcur[row * 64 + ((((ks << 2) | quad)) ^ (lr & 7)) * 8];
            }
        #pragma unroll
        for (int tm = 0; tm < 2; ++tm)
            #pragma unroll
            for (int td = 0; td < 4; ++td) {
                oacc[tm][td] = MFMA(pa[tm][0], vb[td][0], oacc[tm][td], 0, 0, 0);
                oacc[tm][td] = MFMA(pa[tm][1], vb[td][1], oacc[tm][td], 0, 0, 0);
            }
        __syncthreads();   // reads of Kcur/Vcur done; drains next-tile DMA
        ushort* tp2;
        tp2 = Kcur; Kcur = Knxt; Knxt = tp2;
        tp2 = Vcur; Vcur = Vnxt; Vnxt = tp2;
    }

    const int bb = bh >> 4, head = bh & 15;
    #pragma unroll
    for (int tm = 0; tm < 2; ++tm)
        #pragma unroll
        for (int r = 0; r < 4; ++r) {
            float l = lrow[tm][r];
            l += __shfl_xor(l, 1);
            l += __shfl_xor(l, 2);
            l += __shfl_xor(l, 4);
            l += __shfl_xor(l, 8);
            const float inv = 1.f / l;
            const int row = i0 + w * 32 + tm * 16 + quad * 4 + r;
            #pragma unroll
            for (int td = 0; td < 4; ++td) {
                nts2(O + (size_t)(bb * SEQ + row) * DIM + head * HD + td * 16 + lr,
                     f2b(oacc[tm][td][r] * inv));
            }
        }
}

extern "C" void kernel_launch(void* const* d_in, const int* in_sizes, int n_in,
                              void* d_out, int out_size, void* d_ws, size_t ws_size,
                              hipStream_t stream)
{
    const float* x  = (const float*)d_in[0];
    const float* Wq = (const float*)d_in[1];
    const float* bq = (const float*)d_in[2];
    const float* Wv = (const float*)d_in[3];
    const float* bv = (const float*)d_in[4];
    const float* Wo = (const float*)d_in[5];
    const float* bo = (const float*)d_in[6];

    // ws: Qh 8MB | Vt 8MB | R 8MB (xb for QV, then Oh) | [Wob 2MB if room]
    ushort* Qh = (ushort*)d_ws;
    ushort* Vt = Qh + (size_t)BATCH * HEADS * SEQ * HD;
    ushort* R  = Vt + (size_t)BATCH * HEADS * SEQ * HD;
    const size_t WS3 = (size_t)3 * BATCH * HEADS * SEQ * HD * 2;   // 24 MB
    const size_t WOB = (size_t)DIM * DIM * 2;                      // 2 MB
    const int doWo = ws_size >= WS3 + WOB;
    ushort* Wob = (ushort*)((char*)d_ws + WS3);

    // d_out (16MB) as pre-phase scratch (fully overwritten by gemm_out):
    // Wqb [0,2MB) | Wvb [2,4MB) | sq [4,4.25MB)
    ushort* Wqb = (ushort*)d_out;
    ushort* Wvb = Wqb + (size_t)DIM * DIM;
    float*  sqG = (float*)(Wvb + (size_t)DIM * DIM);

    conv_all<<<3584, 256, 0, stream>>>(x, Wq, Wv, Wo, R, Wqb, Wvb, Wob, doWo);
    gemm_qv<<<dim3(16, 32), 256, 0, stream>>>(R, Wqb, Wvb, bq, bv, Qh, Vt, sqG);
    attn_mfma<<<512, 256, 0, stream>>>(Qh, Vt, sqG, R);   // Oh overwrites xb
    if (doWo) {
        gemm_out<1><<<dim3(16, 32), 256, 0, stream>>>(R, Wob, nullptr, bo,
                                                      (float*)d_out);
    } else {
        gemm_out<0><<<dim3(16, 32), 256, 0, stream>>>(R, nullptr, Wo, bo,
                                                      (float*)d_out);
    }
}